// Round 1
// baseline (48799.707 us; speedup 1.0000x reference)
//
#include <hip/hip_runtime.h>
#include <math.h>

// ---------------------------------------------------------------------------
// RGN: 2-layer biLSTM (T=512,B=32,H=800) -> linear/softmax/dihedral -> NeRF chain
// Round 0: all-fp32 correctness-first implementation.
//   - persistent 200-block recurrent kernel (100 per direction, 8 hidden/block)
//   - weights LDS-resident (Whh, layer0 Wih); layer1 Wih streamed transposed
//   - per-step grid barrier via monotonic device-scope atomic counter
// ---------------------------------------------------------------------------

#define TT 512
#define BB 32
#define HH 800
#define DIN 41
#define DINP 44                 // x padded to 44 cols (zeros)
#define K0T (DINP + HH)         // 844
#define K1A 1600                // layer1 input width (2H)
#define GSTR (2 * HH * BB)      // 51200 floats per timestep of h1/h2
#define NBLK 200
#define BPD 100                 // blocks per direction
#define HB 8                    // hidden units per block
#define GP_OFF (K0T * 32)       // 27008 floats: start of partial buffer in LDS
#define SMEM_FLOATS (K0T * 32 + 4 * 32 * 33)   // 27008 + 4224 = 31232
#define SMEM_BYTES (SMEM_FLOATS * 4)           // 124928 B

// ---------------- workspace layout (float offsets) ----------------
// 0        : unsigned barrier counter
// 8        : sin(alphabet) [60]
// 68       : cos(alphabet) [60]
// 128      : xT  [512][44][32]            (720896)
// 721024   : W1T [2][1600][3200]          (10240000)
// 10961024 : h1  [512][1600][32]          (26214400)
// 37175424 : h2  [512][1600][32]          (26214400)
// 63389824 : angles [512][32][3]          (49152)
// total 63439k floats ~= 254 MB

__device__ __forceinline__ float sigm(float x) { return 1.0f / (1.0f + expf(-x)); }

// Monotonic grid barrier. Safe: ctr >= NBLK*(i+1) implies every block passed
// barrier i (a block cannot reach barrier i+1 without passing barrier i).
__device__ __forceinline__ void gbar(unsigned* ctr, unsigned target) {
    __syncthreads();
    if (threadIdx.x == 0) {
        __hip_atomic_fetch_add(ctr, 1u, __ATOMIC_RELEASE, __HIP_MEMORY_SCOPE_AGENT);
        while (__hip_atomic_load(ctr, __ATOMIC_ACQUIRE, __HIP_MEMORY_SCOPE_AGENT) < target) {
            __builtin_amdgcn_s_sleep(2);
        }
    }
    __syncthreads();
}

#define FMA4(A, S, V)                                       \
    A.x = fmaf((S), (V).x, A.x); A.y = fmaf((S), (V).y, A.y); \
    A.z = fmaf((S), (V).z, A.z); A.w = fmaf((S), (V).w, A.w)

struct Acc { float4 a0, a1, a2, a3; };

// W from LDS [k][32] (conflict-free: 8 distinct float4 per wave, 128B span)
__device__ __forceinline__ void dot_lds(Acc& A, const float* wl, const float* inp,
                                        int lo, int hi, int rq4, int bq4) {
#pragma unroll 4
    for (int k = lo; k < hi; ++k) {
        const float4 w = *(const float4*)(wl + k * 32 + rq4);
        const float4 v = *(const float4*)(inp + (size_t)k * BB + bq4);
        FMA4(A.a0, w.x, v); FMA4(A.a1, w.y, v);
        FMA4(A.a2, w.z, v); FMA4(A.a3, w.w, v);
    }
}

// W from global, transposed layout [k][3200]
__device__ __forceinline__ void dot_gmem(Acc& A, const float* wg, const float* inp,
                                         int lo, int hi, int bq4) {
#pragma unroll 4
    for (int k = lo; k < hi; ++k) {
        const float4 w = *(const float4*)(wg + (size_t)k * 3200);
        const float4 v = *(const float4*)(inp + (size_t)k * BB + bq4);
        FMA4(A.a0, w.x, v); FMA4(A.a1, w.y, v);
        FMA4(A.a2, w.z, v); FMA4(A.a3, w.w, v);
    }
}

__device__ __forceinline__ void store_partials(float* gp, const Acc& A, int ks, int rq4, int bq4) {
    float* q = gp + ((size_t)(ks * 32 + rq4)) * 33 + bq4;
    q[0] = A.a0.x; q[1] = A.a0.y; q[2] = A.a0.z; q[3] = A.a0.w; q += 33;
    q[0] = A.a1.x; q[1] = A.a1.y; q[2] = A.a1.z; q[3] = A.a1.w; q += 33;
    q[0] = A.a2.x; q[1] = A.a2.y; q[2] = A.a2.z; q[3] = A.a2.w; q += 33;
    q[0] = A.a3.x; q[1] = A.a3.y; q[2] = A.a3.z; q[3] = A.a3.w;
}

__device__ __forceinline__ void lstm_epilogue(const float* gp, int jloc, int bb,
                                              float bi, float bf, float bg, float bo,
                                              float& creg, float* hout) {
    const float* q = gp + bb;
#define GSUM(r) (q[(r) * 33] + q[(r) * 33 + 1056] + q[(r) * 33 + 2112] + q[(r) * 33 + 3168])
    const float gi_ = GSUM(jloc) + bi;
    const float gf_ = GSUM(8 + jloc) + bf;
    const float gc_ = GSUM(16 + jloc) + bg;
    const float go_ = GSUM(24 + jloc) + bo;
#undef GSUM
    const float cn = sigm(gf_) * creg + sigm(gi_) * tanhf(gc_);
    creg = cn;
    *hout = sigm(go_) * tanhf(cn);
}

// ---------------------------------------------------------------------------
__global__ __launch_bounds__(256, 1) void rnn_kernel(
    const float* __restrict__ xT,
    float* __restrict__ h1,
    float* __restrict__ h2,
    const float* __restrict__ W1T,
    const float* __restrict__ Wih_f0, const float* __restrict__ Whh_f0, const float* __restrict__ b_f0,
    const float* __restrict__ Wih_b0, const float* __restrict__ Whh_b0, const float* __restrict__ b_b0,
    const float* __restrict__ Whh_f1, const float* __restrict__ b_f1,
    const float* __restrict__ Whh_b1, const float* __restrict__ b_b1,
    unsigned* __restrict__ ctr)
{
    extern __shared__ float smem[];
    float* wl = smem;            // [k][32] weights, k up to 844
    float* gp = smem + GP_OFF;   // [4][32][33] partial sums

    const int tid  = threadIdx.x;
    const int dir  = blockIdx.x / BPD;   // 0 fwd, 1 bwd
    const int blk  = blockIdx.x % BPD;
    const int j0   = blk * HB;
    const int rq4  = (tid & 7) * 4;         // 4 consecutive local gate-rows
    const int bq4  = ((tid >> 3) & 7) * 4;  // 4 consecutive batch cols
    const int ks   = tid >> 6;              // k-split slice == wave id
    const int jloc = tid >> 5;              // epilogue: hidden unit 0..7
    const int bb   = tid & 31;              // epilogue: batch 0..31

    const float* Wih0 = dir ? Wih_b0 : Wih_f0;
    const float* Whh0 = dir ? Whh_b0 : Whh_f0;
    const float* bs0  = dir ? b_b0  : b_f0;
    const float* Whh1 = dir ? Whh_b1 : Whh_f1;
    const float* bs1  = dir ? b_b1  : b_f1;
    const float* W1Td = W1T + (size_t)dir * (size_t)K1A * 3200;

    unsigned nb = 0;

    // =========================== phase 0: layer 0 ===========================
    // LDS weights: wl[k][r]; k<44: padded Wih cols; k>=44: Whh col k-44.
    // local row r = gate*8 + jl  ->  global row gate*800 + j0 + jl
    for (int idx = tid; idx < K0T * 32; idx += 256) {
        const int k = idx >> 5, r = idx & 31;
        const int grow = (r >> 3) * HH + j0 + (r & 7);
        float w;
        if (k < DINP) w = (k < DIN) ? Wih0[grow * DIN + k] : 0.0f;
        else          w = Whh0[grow * HH + (k - DINP)];
        wl[k * 32 + r] = w;
    }
    float bi = bs0[0 * HH + j0 + jloc];
    float bf = bs0[1 * HH + j0 + jloc];
    float bg = bs0[2 * HH + j0 + jloc];
    float bo = bs0[3 * HH + j0 + jloc];
    __syncthreads();

    float creg = 0.0f;
    {
        const int klo = ks * 211, khi = klo + 211;   // 844/4
        for (int s = 0; s < TT; ++s) {
            const int t = dir ? (TT - 1 - s) : s;
            Acc A; A.a0 = make_float4(0.f, 0.f, 0.f, 0.f); A.a1 = A.a0; A.a2 = A.a0; A.a3 = A.a0;
            {   // x part (only wave 0's range intersects [0,44))
                const int hi = khi < DINP ? khi : DINP;
                if (klo < hi) dot_lds(A, wl, xT + (size_t)t * DINP * BB, klo, hi, rq4, bq4);
            }
            if (s > 0) {   // h part: read own-direction h1 of previous step
                const int lo = klo > DINP ? klo : DINP;
                if (lo < khi) {
                    const int tp = dir ? t + 1 : t - 1;
                    const float* inp = h1 + (size_t)tp * GSTR + (size_t)dir * HH * BB - (size_t)DINP * BB;
                    dot_lds(A, wl, inp, lo, khi, rq4, bq4);
                }
            }
            store_partials(gp, A, ks, rq4, bq4);
            __syncthreads();
            lstm_epilogue(gp, jloc, bb, bi, bf, bg, bo, creg,
                          h1 + (size_t)t * GSTR + (size_t)dir * HH * BB + (size_t)(j0 + jloc) * BB + bb);
            ++nb;
            gbar(ctr, (unsigned)NBLK * nb);
        }
    }

    // =========================== phase 1: layer 1 ===========================
    for (int idx = tid; idx < HH * 32; idx += 256) {
        const int k = idx >> 5, r = idx & 31;
        const int grow = (r >> 3) * HH + j0 + (r & 7);
        wl[k * 32 + r] = Whh1[grow * HH + k];
    }
    bi = bs1[0 * HH + j0 + jloc];
    bf = bs1[1 * HH + j0 + jloc];
    bg = bs1[2 * HH + j0 + jloc];
    bo = bs1[3 * HH + j0 + jloc];
    __syncthreads();

    creg = 0.0f;
    {
        const int kloA = ks * 400, khiA = kloA + 400;  // input-proj k-range (1600/4)
        const int kloB = ks * 200, khiB = kloB + 200;  // recurrent k-range (800/4)
        // rows rq4..rq4+3 are within one gate: gate = rq4>>3, jl base = rq4&4
        const int gbase = (rq4 >> 3) * HH + j0 + (rq4 & 4);
        for (int s = 0; s < TT; ++s) {
            const int t = dir ? (TT - 1 - s) : s;
            Acc A; A.a0 = make_float4(0.f, 0.f, 0.f, 0.f); A.a1 = A.a0; A.a2 = A.a0; A.a3 = A.a0;
            // input projection: full bidirectional h1[t], W streamed (transposed)
            dot_gmem(A, W1Td + gbase, h1 + (size_t)t * GSTR, kloA, khiA, bq4);
            if (s > 0) {
                const int tp = dir ? t + 1 : t - 1;
                dot_lds(A, wl, h2 + (size_t)tp * GSTR + (size_t)dir * HH * BB, kloB, khiB, rq4, bq4);
            }
            store_partials(gp, A, ks, rq4, bq4);
            __syncthreads();
            lstm_epilogue(gp, jloc, bb, bi, bf, bg, bo, creg,
                          h2 + (size_t)t * GSTR + (size_t)dir * HH * BB + (size_t)(j0 + jloc) * BB + bb);
            ++nb;
            gbar(ctr, (unsigned)NBLK * nb);
        }
    }
}

// ---------------------------------------------------------------------------
// prep: build xT [t][i][b] (zero-padded to 44), sin/cos(alphabet), zero ctr
__global__ void prep_kernel(const float* __restrict__ x, const float* __restrict__ alphabet,
                            float* __restrict__ xT, float* __restrict__ sin_t,
                            float* __restrict__ cos_t, unsigned* __restrict__ ctr) {
    const int gid = blockIdx.x * blockDim.x + threadIdx.x;
    const int nth = gridDim.x * blockDim.x;
    for (int idx = gid; idx < TT * DINP * BB; idx += nth) {
        const int t = idx / (DINP * BB);
        const int rem = idx - t * (DINP * BB);
        const int i = rem >> 5, b = rem & 31;
        xT[idx] = (i < DIN) ? x[((size_t)t * BB + b) * DIN + i] : 0.0f;
    }
    if (gid < 60) { sin_t[gid] = sinf(alphabet[gid]); cos_t[gid] = cosf(alphabet[gid]); }
    if (gid == 0) *ctr = 0u;
}

// transpose layer-1 input weights: W1T[dir][k][g] = Wih1_dir[g][k]
__global__ void transpose_w1(const float* __restrict__ Wf, const float* __restrict__ Wb,
                             float* __restrict__ W1T) {
    __shared__ float tile[32][33];
    const int bid = blockIdx.x;
    const int dirIdx = bid / 5000;
    const int rem = bid % 5000;
    const int kt = rem / 100, gt = rem % 100;
    const float* W = dirIdx ? Wb : Wf;
    float* out = W1T + (size_t)dirIdx * K1A * 3200;
    for (int p = threadIdx.x; p < 1024; p += 256) {
        const int gl = p >> 5, kl = p & 31;
        tile[gl][kl] = W[((size_t)(gt * 32 + gl)) * K1A + kt * 32 + kl];
    }
    __syncthreads();
    for (int p = threadIdx.x; p < 1024; p += 256) {
        const int kl = p >> 5, gl = p & 31;
        out[((size_t)(kt * 32 + kl)) * 3200 + gt * 32 + gl] = tile[gl][kl];
    }
}

// logits -> softmax -> dihedral angles (softmax denom & max-shift cancel in atan2)
__global__ __launch_bounds__(640, 1) void head_kernel(
    const float* __restrict__ h2, const float* __restrict__ Wl, const float* __restrict__ bl,
    const float* __restrict__ sin_t, const float* __restrict__ cos_t,
    float* __restrict__ angles) {
    __shared__ float pl[20][33];
    __shared__ float mx[32];
    const int t = blockIdx.x;
    const int a = threadIdx.x / 32;
    const int b = threadIdx.x & 31;
    const float* hb = h2 + (size_t)t * GSTR;
    if (a < 20) {
        float acc = bl[a];
        const float* wr = Wl + (size_t)a * K1A;
#pragma unroll 4
        for (int k = 0; k < K1A; ++k) acc = fmaf(wr[k], hb[(size_t)k * BB + b], acc);
        pl[a][b] = acc;
    }
    __syncthreads();
    if (threadIdx.x < 32) {
        float m = pl[0][threadIdx.x];
        for (int i = 1; i < 20; ++i) m = fmaxf(m, pl[i][threadIdx.x]);
        mx[threadIdx.x] = m;
    }
    __syncthreads();
    if (a < 20) pl[a][b] = expf(pl[a][b] - mx[b]);
    __syncthreads();
    if (threadIdx.x < 96) {
        const int c = threadIdx.x / 32, b2 = threadIdx.x & 31;
        float y = 0.f, xx = 0.f;
        for (int i = 0; i < 20; ++i) {
            const float e = pl[i][b2];
            y  = fmaf(e, sin_t[i * 3 + c], y);
            xx = fmaf(e, cos_t[i * 3 + c], xx);
        }
        angles[((size_t)t * BB + b2) * 3 + c] = atan2f(y, xx);
    }
}

// sequential NeRF coordinate extension, one lane per batch element
__global__ void coords_kernel(const float* __restrict__ angles, float* __restrict__ out) {
    const int b = threadIdx.x;
    if (b >= BB) return;
    const float rs[3]  = {1.458f, 1.525f, 1.33f};
    const float ths[3] = {2.124f, 1.941f, 2.028f};
    float ct[3], st[3];
#pragma unroll
    for (int k = 0; k < 3; ++k) { ct[k] = cosf(ths[k]); st[k] = sinf(ths[k]); }
    float pax = 0.f,     pay = 0.f, paz = 0.f;
    float pbx = 1.458f,  pby = 0.f, pbz = 0.f;
    float pcx = 2.f,     pcy = 1.f, pcz = 0.f;
    for (int n = 0; n < 3 * TT; ++n) {
        const int t = n / 3;
        const int k = n - 3 * t;
        const float phi = angles[((size_t)t * BB + b) * 3 + k];
        float ux = pcx - pbx, uy = pcy - pby, uz = pcz - pbz;
        const float il = rsqrtf(ux * ux + uy * uy + uz * uz);
        const float bcx = ux * il, bcy = uy * il, bcz = uz * il;
        const float wx = pbx - pax, wy = pby - pay, wz = pbz - paz;
        float cx = wy * bcz - wz * bcy, cy = wz * bcx - wx * bcz, cz = wx * bcy - wy * bcx;
        const float iln = rsqrtf(cx * cx + cy * cy + cz * cz);
        const float nx = cx * iln, ny = cy * iln, nz = cz * iln;
        const float mxv = ny * bcz - nz * bcy, myv = nz * bcx - nx * bcz, mzv = nx * bcy - ny * bcx;
        float sp, cp;
        __sincosf(phi, &sp, &cp);
        const float rr = rs[k], cth = ct[k], sth = st[k];
        const float dx = pcx - rr * cth * bcx + rr * sth * (cp * mxv + sp * nx);
        const float dy = pcy - rr * cth * bcy + rr * sth * (cp * myv + sp * ny);
        const float dz = pcz - rr * cth * bcz + rr * sth * (cp * mzv + sp * nz);
        float* o = out + ((size_t)n * BB + b) * 3;
        o[0] = dx; o[1] = dy; o[2] = dz;
        pax = pbx; pay = pby; paz = pbz;
        pbx = pcx; pby = pcy; pbz = pcz;
        pcx = dx;  pcy = dy;  pcz = dz;
    }
}

// ---------------------------------------------------------------------------
extern "C" void kernel_launch(void* const* d_in, const int* in_sizes, int n_in,
                              void* d_out, int out_size, void* d_ws, size_t ws_size,
                              hipStream_t stream) {
    (void)in_sizes; (void)n_in; (void)out_size; (void)ws_size;
    const float* x      = (const float*)d_in[0];
    const float* Wih_f0 = (const float*)d_in[1];
    const float* Whh_f0 = (const float*)d_in[2];
    const float* b_f0   = (const float*)d_in[3];
    const float* Wih_b0 = (const float*)d_in[4];
    const float* Whh_b0 = (const float*)d_in[5];
    const float* b_b0   = (const float*)d_in[6];
    const float* Wih_f1 = (const float*)d_in[7];
    const float* Whh_f1 = (const float*)d_in[8];
    const float* b_f1   = (const float*)d_in[9];
    const float* Wih_b1 = (const float*)d_in[10];
    const float* Whh_b1 = (const float*)d_in[11];
    const float* b_b1   = (const float*)d_in[12];
    const float* Wl     = (const float*)d_in[13];
    const float* bl     = (const float*)d_in[14];
    const float* alphabet = (const float*)d_in[15];

    float* ws = (float*)d_ws;
    unsigned* ctr = (unsigned*)d_ws;
    float* sin_t  = ws + 8;
    float* cos_t  = ws + 68;
    float* xT     = ws + 128;
    float* W1T    = ws + 721024;
    float* h1     = ws + 10961024;
    float* h2     = ws + 37175424;
    float* angles = ws + 63389824;

    // allow >64KB dynamic LDS for the persistent kernel (idempotent, non-stream op)
    (void)hipFuncSetAttribute((const void*)rnn_kernel,
                              hipFuncAttributeMaxDynamicSharedMemorySize, SMEM_BYTES);

    prep_kernel<<<512, 256, 0, stream>>>(x, alphabet, xT, sin_t, cos_t, ctr);
    transpose_w1<<<10000, 256, 0, stream>>>(Wih_f1, Wih_b1, W1T);
    rnn_kernel<<<NBLK, 256, SMEM_BYTES, stream>>>(xT, h1, h2, W1T,
        Wih_f0, Whh_f0, b_f0, Wih_b0, Whh_b0, b_b0,
        Whh_f1, b_f1, Whh_b1, b_b1, ctr);
    head_kernel<<<TT, 640, 0, stream>>>(h2, Wl, bl, sin_t, cos_t, angles);
    coords_kernel<<<1, 64, 0, stream>>>(angles, (float*)d_out);
}

// Round 3
// 17862.982 us; speedup vs baseline: 2.7319x; 2.7319x over previous
//
#include <hip/hip_runtime.h>
#include <math.h>

// ---------------------------------------------------------------------------
// RGN: 2-layer biLSTM (T=512,B=32,H=800) -> linear/softmax/dihedral -> NeRF chain
// Round 3: fused MFMA recurrence, register-resident weights, small workspace.
//   R2 post-mortem: 390 MB workspace overflowed d_ws -> device fault. This
//   design needs only ~107 MB.
//   - rnn0/rnn1: persistent 200-block kernels (100/dir, 8 hidden units each).
//     Each wave holds its k-slice of the f16 weights as MFMA A-fragments in
//     REGISTERS (rnn1: 152 VGPR) for all 512 steps. Per step: 16x16x32 f16
//     MFMA, 4-way k-split, LDS partial reduce, LSTM epilogue, grid barrier.
//   - h1/h2 stored f16 [t][b][1600] (B-fragment-ready: half8 = 8 consecutive k)
// ---------------------------------------------------------------------------

#define TT 512
#define BB 32
#define HH 800
#define DIN 41
#define XPAD 64                // x padded to 64 cols (zeros) -> 2 clean k-steps
#define KROW 1600              // h row length in k (both directions packed)
#define NBLK 200
#define BPD 100                // blocks per direction

typedef _Float16 f16;
typedef _Float16 half8 __attribute__((ext_vector_type(8)));
typedef float floatx4 __attribute__((ext_vector_type(4)));

// ---------------- workspace layout (float-slot offsets), total ~107 MB -----
// u32[0] = ctr0, u32[16] = ctr1
#define OFF_XT   32                         // f16 [512][32][64]    (524288 slots)
#define OFF_H1   (OFF_XT + 524288)          // f16 [512][32][1600]  (13107200 slots)
#define OFF_H2   (OFF_H1 + 13107200)        // f16 [512][32][1600]  (13107200 slots)
#define OFF_ANG  (OFF_H2 + 13107200)        // f32 [512][32][3]     (49152)
#define OFF_SIN  (OFF_ANG + 49152)
#define OFF_COS  (OFF_SIN + 64)

__device__ __forceinline__ float sigm(float x) { return 1.0f / (1.0f + expf(-x)); }

// Monotonic grid barrier (lap-safe: a block cannot reach barrier i+1 without
// passing barrier i). Release orders this block's h-stores to agent scope;
// acquire invalidates stale L1/L2 lines (validated cross-XCD in R1).
__device__ __forceinline__ void gbar(unsigned* ctr, unsigned target) {
    __syncthreads();
    if (threadIdx.x == 0) {
        __hip_atomic_fetch_add(ctr, 1u, __ATOMIC_RELEASE, __HIP_MEMORY_SCOPE_AGENT);
        while (__hip_atomic_load(ctr, __ATOMIC_ACQUIRE, __HIP_MEMORY_SCOPE_AGENT) < target) {
            __builtin_amdgcn_s_sleep(2);
        }
    }
    __syncthreads();
}

__device__ __forceinline__ half8 cvt8(const float* p) {
    half8 r;
#pragma unroll
    for (int i = 0; i < 8; ++i) r[i] = (f16)p[i];
    return r;
}

// ===========================================================================
// rnn0: layer 0.  K = 64 (xT) + 800 (h1 prev, own dir) = 27 k-steps of 32.
// ===========================================================================
__global__ __launch_bounds__(256, 1) void rnn0_kernel(
    const f16* __restrict__ xT, f16* __restrict__ h1,
    const float* __restrict__ Wih_f0, const float* __restrict__ Whh_f0, const float* __restrict__ b_f0,
    const float* __restrict__ Wih_b0, const float* __restrict__ Whh_b0, const float* __restrict__ b_b0,
    unsigned* __restrict__ ctr)
{
    __shared__ float gbuf[4][32][33];
    __shared__ f16  hbuf[256];

    const int tid  = threadIdx.x;
    const int dir  = blockIdx.x / BPD;
    const int blk  = blockIdx.x % BPD;
    const int j0   = blk * 8;
    const int w    = tid >> 6;          // wave id = k-slice
    const int lane = tid & 63;
    const int l15  = lane & 15;
    const int quad = lane >> 4;
    const int jl   = tid >> 5;          // epilogue: hidden unit 0..7
    const int bb   = tid & 31;          // epilogue: batch

    const float* Wih = dir ? Wih_b0 : Wih_f0;
    const float* Whh = dir ? Whh_b0 : Whh_f0;
    const float* bs  = dir ? b_b0  : b_f0;

    const int kt0 = (w * 27) >> 2;          // 0,6,13,20
    const int kt1 = ((w + 1) * 27) >> 2;    // 6,13,20,27

    // A-fragments in registers: afr[mt][i] = W[row mt*16+l15][k = (kt0+i)*32 + quad*8 ..+7]
    half8 afr[2][7];
#pragma unroll
    for (int mt = 0; mt < 2; ++mt) {
        const int r = mt * 16 + l15;
        const int grow = (r >> 3) * HH + j0 + (r & 7);
#pragma unroll
        for (int i = 0; i < 7; ++i) {
            const int ktg = kt0 + i;
            half8 v;
#pragma unroll
            for (int jj = 0; jj < 8; ++jj) v[jj] = (f16)0.f;
            if (ktg < kt1) {
                if (ktg < 2) {          // Wih cols (41 wide, zero-padded to 64)
#pragma unroll
                    for (int jj = 0; jj < 8; ++jj) {
                        const int k = ktg * 32 + quad * 8 + jj;
                        if (k < DIN) v[jj] = (f16)Wih[(size_t)grow * DIN + k];
                    }
                } else {                // Whh cols
                    v = cvt8(Whh + (size_t)grow * HH + (ktg - 2) * 32 + quad * 8);
                }
            }
            afr[mt][i] = v;
        }
    }
    const float bi = bs[0 * HH + j0 + jl], bf = bs[1 * HH + j0 + jl],
                bg = bs[2 * HH + j0 + jl], bo = bs[3 * HH + j0 + jl];

    float creg = 0.0f;
    for (int s = 0; s < TT; ++s) {
        const int t  = dir ? (TT - 1 - s) : s;
        const int tp = dir ? t + 1 : t - 1;
        floatx4 acc[2][2];
        acc[0][0] = (floatx4)0.f; acc[0][1] = (floatx4)0.f;
        acc[1][0] = (floatx4)0.f; acc[1][1] = (floatx4)0.f;

        const f16* xrow = xT + (size_t)t * BB * XPAD;
        const f16* hrow = h1 + (size_t)tp * BB * KROW + dir * HH;   // valid iff s>0
#pragma unroll
        for (int i = 0; i < 7; ++i) {
            const int ktg = kt0 + i;
            if (ktg < kt1) {
                const bool isx = (ktg < 2);
                if (isx || s > 0) {
                    half8 b0, b1;
                    if (isx) {
                        const f16* p = xrow + ktg * 32 + quad * 8;
                        b0 = *(const half8*)(p + (size_t)l15 * XPAD);
                        b1 = *(const half8*)(p + (size_t)(16 + l15) * XPAD);
                    } else {
                        const f16* p = hrow + (ktg - 2) * 32 + quad * 8;
                        b0 = *(const half8*)(p + (size_t)l15 * KROW);
                        b1 = *(const half8*)(p + (size_t)(16 + l15) * KROW);
                    }
                    acc[0][0] = __builtin_amdgcn_mfma_f32_16x16x32_f16(afr[0][i], b0, acc[0][0], 0, 0, 0);
                    acc[0][1] = __builtin_amdgcn_mfma_f32_16x16x32_f16(afr[0][i], b1, acc[0][1], 0, 0, 0);
                    acc[1][0] = __builtin_amdgcn_mfma_f32_16x16x32_f16(afr[1][i], b0, acc[1][0], 0, 0, 0);
                    acc[1][1] = __builtin_amdgcn_mfma_f32_16x16x32_f16(afr[1][i], b1, acc[1][1], 0, 0, 0);
                }
            }
        }
        // per-wave partials -> LDS   (D layout: row = quad*4+reg, col = l15)
#pragma unroll
        for (int mt = 0; mt < 2; ++mt)
#pragma unroll
            for (int nt = 0; nt < 2; ++nt)
#pragma unroll
                for (int rg = 0; rg < 4; ++rg)
                    gbuf[w][mt * 16 + quad * 4 + rg][nt * 16 + l15] = acc[mt][nt][rg];
        __syncthreads();
        {   // epilogue: thread (jl, bb)
            float gi_ = bi, gf_ = bf, gc_ = bg, go_ = bo;
#pragma unroll
            for (int ww = 0; ww < 4; ++ww) {
                gi_ += gbuf[ww][jl][bb];
                gf_ += gbuf[ww][8 + jl][bb];
                gc_ += gbuf[ww][16 + jl][bb];
                go_ += gbuf[ww][24 + jl][bb];
            }
            const float cn = sigm(gf_) * creg + sigm(gi_) * tanhf(gc_);
            creg = cn;
            hbuf[bb * 8 + jl] = (f16)(sigm(go_) * tanhf(cn));
        }
        __syncthreads();
        if (tid < BB)
            *(half8*)(h1 + ((size_t)t * BB + tid) * KROW + dir * HH + j0) =
                *(const half8*)(hbuf + tid * 8);
        gbar(ctr, (unsigned)NBLK * (unsigned)(s + 1));
    }
}

// ===========================================================================
// rnn1: layer 1.  K = 1600 (h1[t], both dirs) + 800 (h2 prev) = 75 k-steps.
// ===========================================================================
__global__ __launch_bounds__(256, 1) void rnn1_kernel(
    const f16* __restrict__ h1, f16* __restrict__ h2,
    const float* __restrict__ Wih_f1, const float* __restrict__ Whh_f1, const float* __restrict__ b_f1,
    const float* __restrict__ Wih_b1, const float* __restrict__ Whh_b1, const float* __restrict__ b_b1,
    unsigned* __restrict__ ctr)
{
    __shared__ float gbuf[4][32][33];
    __shared__ f16  hbuf[256];

    const int tid  = threadIdx.x;
    const int dir  = blockIdx.x / BPD;
    const int blk  = blockIdx.x % BPD;
    const int j0   = blk * 8;
    const int w    = tid >> 6;
    const int lane = tid & 63;
    const int l15  = lane & 15;
    const int quad = lane >> 4;
    const int jl   = tid >> 5;
    const int bb   = tid & 31;

    const float* Wih = dir ? Wih_b1 : Wih_f1;
    const float* Whh = dir ? Whh_b1 : Whh_f1;
    const float* bs  = dir ? b_b1  : b_f1;

    const int kt0 = (w * 75) >> 2;          // 0,18,37,56
    const int kt1 = ((w + 1) * 75) >> 2;    // 18,37,56,75

    half8 afr[2][19];                       // 152 VGPRs of weights
#pragma unroll
    for (int mt = 0; mt < 2; ++mt) {
        const int r = mt * 16 + l15;
        const int grow = (r >> 3) * HH + j0 + (r & 7);
#pragma unroll
        for (int i = 0; i < 19; ++i) {
            const int ktg = kt0 + i;
            half8 v;
#pragma unroll
            for (int jj = 0; jj < 8; ++jj) v[jj] = (f16)0.f;
            if (ktg < kt1) {
                if (ktg < 50) v = cvt8(Wih + (size_t)grow * KROW + ktg * 32 + quad * 8);
                else          v = cvt8(Whh + (size_t)grow * HH + (ktg - 50) * 32 + quad * 8);
            }
            afr[mt][i] = v;
        }
    }
    const float bi = bs[0 * HH + j0 + jl], bf = bs[1 * HH + j0 + jl],
                bg = bs[2 * HH + j0 + jl], bo = bs[3 * HH + j0 + jl];

    float creg = 0.0f;
    for (int s = 0; s < TT; ++s) {
        const int t  = dir ? (TT - 1 - s) : s;
        const int tp = dir ? t + 1 : t - 1;
        floatx4 acc[2][2];
        acc[0][0] = (floatx4)0.f; acc[0][1] = (floatx4)0.f;
        acc[1][0] = (floatx4)0.f; acc[1][1] = (floatx4)0.f;

        const f16* h1row = h1 + (size_t)t * BB * KROW;               // static input
        const f16* h2row = h2 + (size_t)tp * BB * KROW + dir * HH;   // valid iff s>0
#pragma unroll
        for (int i = 0; i < 19; ++i) {
            const int ktg = kt0 + i;
            if (ktg < kt1) {
                const bool isin = (ktg < 50);
                if (isin || s > 0) {
                    half8 b0, b1;
                    if (isin) {
                        const f16* p = h1row + ktg * 32 + quad * 8;
                        b0 = *(const half8*)(p + (size_t)l15 * KROW);
                        b1 = *(const half8*)(p + (size_t)(16 + l15) * KROW);
                    } else {
                        const f16* p = h2row + (ktg - 50) * 32 + quad * 8;
                        b0 = *(const half8*)(p + (size_t)l15 * KROW);
                        b1 = *(const half8*)(p + (size_t)(16 + l15) * KROW);
                    }
                    acc[0][0] = __builtin_amdgcn_mfma_f32_16x16x32_f16(afr[0][i], b0, acc[0][0], 0, 0, 0);
                    acc[0][1] = __builtin_amdgcn_mfma_f32_16x16x32_f16(afr[0][i], b1, acc[0][1], 0, 0, 0);
                    acc[1][0] = __builtin_amdgcn_mfma_f32_16x16x32_f16(afr[1][i], b0, acc[1][0], 0, 0, 0);
                    acc[1][1] = __builtin_amdgcn_mfma_f32_16x16x32_f16(afr[1][i], b1, acc[1][1], 0, 0, 0);
                }
            }
        }
#pragma unroll
        for (int mt = 0; mt < 2; ++mt)
#pragma unroll
            for (int nt = 0; nt < 2; ++nt)
#pragma unroll
                for (int rg = 0; rg < 4; ++rg)
                    gbuf[w][mt * 16 + quad * 4 + rg][nt * 16 + l15] = acc[mt][nt][rg];
        __syncthreads();
        {
            float gi_ = bi, gf_ = bf, gc_ = bg, go_ = bo;
#pragma unroll
            for (int ww = 0; ww < 4; ++ww) {
                gi_ += gbuf[ww][jl][bb];
                gf_ += gbuf[ww][8 + jl][bb];
                gc_ += gbuf[ww][16 + jl][bb];
                go_ += gbuf[ww][24 + jl][bb];
            }
            const float cn = sigm(gf_) * creg + sigm(gi_) * tanhf(gc_);
            creg = cn;
            hbuf[bb * 8 + jl] = (f16)(sigm(go_) * tanhf(cn));
        }
        __syncthreads();
        if (tid < BB)
            *(half8*)(h2 + ((size_t)t * BB + tid) * KROW + dir * HH + j0) =
                *(const half8*)(hbuf + tid * 8);
        gbar(ctr, (unsigned)NBLK * (unsigned)(s + 1));
    }
}

// ---------------------------------------------------------------------------
// prep: xT f16 [t][b][64] zero-padded, sin/cos tables, zero barrier counters
__global__ void prep_kernel(const float* __restrict__ x, const float* __restrict__ alphabet,
                            f16* __restrict__ xT, float* __restrict__ sin_t,
                            float* __restrict__ cos_t, unsigned* __restrict__ ctr0,
                            unsigned* __restrict__ ctr1) {
    const int gid = blockIdx.x * blockDim.x + threadIdx.x;
    const int nth = gridDim.x * blockDim.x;
    for (int idx = gid; idx < TT * BB * XPAD; idx += nth) {
        const int tb = idx >> 6;            // t*32+b
        const int i  = idx & 63;
        xT[idx] = (i < DIN) ? (f16)x[(size_t)tb * DIN + i] : (f16)0.f;
    }
    if (gid < 60) { sin_t[gid] = sinf(alphabet[gid]); cos_t[gid] = cosf(alphabet[gid]); }
    if (gid == 0) *ctr0 = 0u;
    if (gid == 1) *ctr1 = 0u;
}

// logits -> softmax -> dihedral angles (h2 now f16, [t][b][k])
__global__ __launch_bounds__(640, 1) void head_kernel(
    const f16* __restrict__ h2, const float* __restrict__ Wl, const float* __restrict__ bl,
    const float* __restrict__ sin_t, const float* __restrict__ cos_t,
    float* __restrict__ angles) {
    __shared__ float pl[20][33];
    __shared__ float mx[32];
    const int t = blockIdx.x;
    const int a = threadIdx.x / 32;
    const int b = threadIdx.x & 31;
    if (a < 20) {
        float acc = bl[a];
        const float* wr = Wl + (size_t)a * KROW;
        const f16*   hr = h2 + ((size_t)t * BB + b) * KROW;
        for (int k8 = 0; k8 < KROW / 8; ++k8) {
            const half8 hv = *(const half8*)(hr + k8 * 8);
#pragma unroll
            for (int j = 0; j < 8; ++j) acc = fmaf(wr[k8 * 8 + j], (float)hv[j], acc);
        }
        pl[a][b] = acc;
    }
    __syncthreads();
    if (threadIdx.x < 32) {
        float m = pl[0][threadIdx.x];
        for (int i = 1; i < 20; ++i) m = fmaxf(m, pl[i][threadIdx.x]);
        mx[threadIdx.x] = m;
    }
    __syncthreads();
    if (a < 20) pl[a][b] = expf(pl[a][b] - mx[b]);
    __syncthreads();
    if (threadIdx.x < 96) {
        const int c = threadIdx.x / 32, b2 = threadIdx.x & 31;
        float y = 0.f, xx = 0.f;
        for (int i = 0; i < 20; ++i) {
            const float e = pl[i][b2];
            y  = fmaf(e, sin_t[i * 3 + c], y);
            xx = fmaf(e, cos_t[i * 3 + c], xx);
        }
        angles[((size_t)t * BB + b2) * 3 + c] = atan2f(y, xx);
    }
}

// sequential NeRF coordinate extension, one lane per batch element
__global__ void coords_kernel(const float* __restrict__ angles, float* __restrict__ out) {
    const int b = threadIdx.x;
    if (b >= BB) return;
    const float rs[3]  = {1.458f, 1.525f, 1.33f};
    const float ths[3] = {2.124f, 1.941f, 2.028f};
    float ct[3], st[3];
#pragma unroll
    for (int k = 0; k < 3; ++k) { ct[k] = cosf(ths[k]); st[k] = sinf(ths[k]); }
    float pax = 0.f,     pay = 0.f, paz = 0.f;
    float pbx = 1.458f,  pby = 0.f, pbz = 0.f;
    float pcx = 2.f,     pcy = 1.f, pcz = 0.f;
    for (int n = 0; n < 3 * TT; ++n) {
        const int t = n / 3;
        const int k = n - 3 * t;
        const float phi = angles[((size_t)t * BB + b) * 3 + k];
        float ux = pcx - pbx, uy = pcy - pby, uz = pcz - pbz;
        const float il = rsqrtf(ux * ux + uy * uy + uz * uz);
        const float bcx = ux * il, bcy = uy * il, bcz = uz * il;
        const float wx = pbx - pax, wy = pby - pay, wz = pbz - paz;
        float cx = wy * bcz - wz * bcy, cy = wz * bcx - wx * bcz, cz = wx * bcy - wy * bcx;
        const float iln = rsqrtf(cx * cx + cy * cy + cz * cz);
        const float nx = cx * iln, ny = cy * iln, nz = cz * iln;
        const float mxv = ny * bcz - nz * bcy, myv = nz * bcx - nx * bcz, mzv = nx * bcy - ny * bcx;
        float sp, cp;
        __sincosf(phi, &sp, &cp);
        const float rr = rs[k], cth = ct[k], sth = st[k];
        const float dx = pcx - rr * cth * bcx + rr * sth * (cp * mxv + sp * nx);
        const float dy = pcy - rr * cth * bcy + rr * sth * (cp * myv + sp * ny);
        const float dz = pcz - rr * cth * bcz + rr * sth * (cp * mzv + sp * nz);
        float* o = out + ((size_t)n * BB + b) * 3;
        o[0] = dx; o[1] = dy; o[2] = dz;
        pax = pbx; pay = pby; paz = pbz;
        pbx = pcx; pby = pcy; pbz = pcz;
        pcx = dx;  pcy = dy;  pcz = dz;
    }
}

// ---------------------------------------------------------------------------
extern "C" void kernel_launch(void* const* d_in, const int* in_sizes, int n_in,
                              void* d_out, int out_size, void* d_ws, size_t ws_size,
                              hipStream_t stream) {
    (void)in_sizes; (void)n_in; (void)out_size; (void)ws_size;
    const float* x      = (const float*)d_in[0];
    const float* Wih_f0 = (const float*)d_in[1];
    const float* Whh_f0 = (const float*)d_in[2];
    const float* b_f0   = (const float*)d_in[3];
    const float* Wih_b0 = (const float*)d_in[4];
    const float* Whh_b0 = (const float*)d_in[5];
    const float* b_b0   = (const float*)d_in[6];
    const float* Wih_f1 = (const float*)d_in[7];
    const float* Whh_f1 = (const float*)d_in[8];
    const float* b_f1   = (const float*)d_in[9];
    const float* Wih_b1 = (const float*)d_in[10];
    const float* Whh_b1 = (const float*)d_in[11];
    const float* b_b1   = (const float*)d_in[12];
    const float* Wl     = (const float*)d_in[13];
    const float* bl     = (const float*)d_in[14];
    const float* alphabet = (const float*)d_in[15];

    float* ws = (float*)d_ws;
    unsigned* ctr0 = (unsigned*)d_ws;
    unsigned* ctr1 = (unsigned*)d_ws + 16;
    f16*   xT     = (f16*)(ws + OFF_XT);
    f16*   h1     = (f16*)(ws + OFF_H1);
    f16*   h2     = (f16*)(ws + OFF_H2);
    float* angles = ws + OFF_ANG;
    float* sin_t  = ws + OFF_SIN;
    float* cos_t  = ws + OFF_COS;

    prep_kernel<<<1024, 256, 0, stream>>>(x, alphabet, xT, sin_t, cos_t, ctr0, ctr1);
    rnn0_kernel<<<NBLK, 256, 0, stream>>>(xT, h1,
        Wih_f0, Whh_f0, b_f0, Wih_b0, Whh_b0, b_b0, ctr0);
    rnn1_kernel<<<NBLK, 256, 0, stream>>>(h1, h2,
        Wih_f1, Whh_f1, b_f1, Wih_b1, Whh_b1, b_b1, ctr1);
    head_kernel<<<TT, 640, 0, stream>>>(h2, Wl, bl, sin_t, cos_t, angles);
    coords_kernel<<<1, 64, 0, stream>>>(angles, (float*)d_out);
}

// Round 4
// 17098.222 us; speedup vs baseline: 2.8541x; 1.0447x over previous
//
#include <hip/hip_runtime.h>
#include <math.h>

// ---------------------------------------------------------------------------
// RGN: 2-layer biLSTM (T=512,B=32,H=800) -> linear/softmax/dihedral -> NeRF chain
// Round 4: flag-array grid barrier (kills the 200-long atomic RMW chain).
//   R3 post-mortem: 19.7 us/step with all pipes idle = serialized agent-scope
//   atomics on one cacheline. Now: block i release-stores step to flags[i];
//   wave 0 polls all own-direction flags in parallel (1 LLC round trip),
//   butterfly-min-reduce, one acquire per step. Barriers split per direction.
//   Compute structure unchanged from R3 (register-resident f16 MFMA weights).
// ---------------------------------------------------------------------------

#define TT 512
#define BB 32
#define HH 800
#define DIN 41
#define XPAD 64                // x padded to 64 cols (zeros) -> 2 clean k-steps
#define KROW 1600              // h row length in k (both directions packed)
#define NBLK 200
#define BPD 100                // blocks per direction

typedef _Float16 f16;
typedef _Float16 half8 __attribute__((ext_vector_type(8)));
typedef float floatx4 __attribute__((ext_vector_type(4)));

// ---------------- workspace layout (float-slot offsets), total ~107 MB -----
// u32[0..127]   rnn0 dir0 flags | u32[128..255] rnn0 dir1 flags
// u32[256..383] rnn1 dir0 flags | u32[384..511] rnn1 dir1 flags
#define OFF_XT   512                        // f16 [512][32][64]    (524288 slots)
#define OFF_H1   (OFF_XT + 524288)          // f16 [512][32][1600]  (13107200 slots)
#define OFF_H2   (OFF_H1 + 13107200)        // f16 [512][32][1600]  (13107200 slots)
#define OFF_ANG  (OFF_H2 + 13107200)        // f32 [512][32][3]     (49152)
#define OFF_SIN  (OFF_ANG + 49152)
#define OFF_COS  (OFF_SIN + 64)

__device__ __forceinline__ float sigm(float x) { return 1.0f / (1.0f + expf(-x)); }

// Flag-array grid barrier over n blocks (own direction only).
// Block myidx release-stores `target` (= step+1, monotonic -> lap-safe) to its
// own flag word; wave 0 polls all n flags with relaxed agent-scope loads
// (parallel, one LLC round trip per iteration), min-reduces across the wave,
// then one acquire load invalidates L1/L2 so post-barrier reads are fresh.
__device__ __forceinline__ void fbar(unsigned* flags, int n, int myidx, unsigned target) {
    __syncthreads();
    if (threadIdx.x < 64) {
        if (threadIdx.x == 0)
            __hip_atomic_store(&flags[myidx], target, __ATOMIC_RELEASE, __HIP_MEMORY_SCOPE_AGENT);
        unsigned m;
        do {
            unsigned v = 0xffffffffu;
            for (int i = (int)threadIdx.x; i < n; i += 64) {
                const unsigned f = __hip_atomic_load(&flags[i], __ATOMIC_RELAXED, __HIP_MEMORY_SCOPE_AGENT);
                v = (f < v) ? f : v;
            }
            m = v;
#pragma unroll
            for (int off = 1; off < 64; off <<= 1) {
                const unsigned o = (unsigned)__shfl_xor((int)m, off, 64);
                m = (o < m) ? o : m;
            }
        } while (m < target);
        // acquire: single cache-invalidate per step (L1 per-CU, L2 per-XCD)
        (void)__hip_atomic_load(&flags[myidx], __ATOMIC_ACQUIRE, __HIP_MEMORY_SCOPE_AGENT);
    }
    __syncthreads();
}

__device__ __forceinline__ half8 cvt8(const float* p) {
    half8 r;
#pragma unroll
    for (int i = 0; i < 8; ++i) r[i] = (f16)p[i];
    return r;
}

// ===========================================================================
// rnn0: layer 0.  K = 64 (xT) + 800 (h1 prev, own dir) = 27 k-steps of 32.
// ===========================================================================
__global__ __launch_bounds__(256, 1) void rnn0_kernel(
    const f16* __restrict__ xT, f16* __restrict__ h1,
    const float* __restrict__ Wih_f0, const float* __restrict__ Whh_f0, const float* __restrict__ b_f0,
    const float* __restrict__ Wih_b0, const float* __restrict__ Whh_b0, const float* __restrict__ b_b0,
    unsigned* __restrict__ fl)
{
    __shared__ float gbuf[4][32][33];
    __shared__ f16  hbuf[256];

    const int tid  = threadIdx.x;
    const int dir  = blockIdx.x / BPD;
    const int blk  = blockIdx.x % BPD;
    const int j0   = blk * 8;
    const int w    = tid >> 6;          // wave id = k-slice
    const int lane = tid & 63;
    const int l15  = lane & 15;
    const int quad = lane >> 4;
    const int jl   = tid >> 5;          // epilogue: hidden unit 0..7
    const int bb   = tid & 31;          // epilogue: batch

    unsigned* flags = fl + dir * 128;

    const float* Wih = dir ? Wih_b0 : Wih_f0;
    const float* Whh = dir ? Whh_b0 : Whh_f0;
    const float* bs  = dir ? b_b0  : b_f0;

    const int kt0 = (w * 27) >> 2;          // 0,6,13,20
    const int kt1 = ((w + 1) * 27) >> 2;    // 6,13,20,27

    // A-fragments in registers: afr[mt][i] = W[row mt*16+l15][k = (kt0+i)*32 + quad*8 ..+7]
    half8 afr[2][7];
#pragma unroll
    for (int mt = 0; mt < 2; ++mt) {
        const int r = mt * 16 + l15;
        const int grow = (r >> 3) * HH + j0 + (r & 7);
#pragma unroll
        for (int i = 0; i < 7; ++i) {
            const int ktg = kt0 + i;
            half8 v;
#pragma unroll
            for (int jj = 0; jj < 8; ++jj) v[jj] = (f16)0.f;
            if (ktg < kt1) {
                if (ktg < 2) {          // Wih cols (41 wide, zero-padded to 64)
#pragma unroll
                    for (int jj = 0; jj < 8; ++jj) {
                        const int k = ktg * 32 + quad * 8 + jj;
                        if (k < DIN) v[jj] = (f16)Wih[(size_t)grow * DIN + k];
                    }
                } else {                // Whh cols
                    v = cvt8(Whh + (size_t)grow * HH + (ktg - 2) * 32 + quad * 8);
                }
            }
            afr[mt][i] = v;
        }
    }
    const float bi = bs[0 * HH + j0 + jl], bf = bs[1 * HH + j0 + jl],
                bg = bs[2 * HH + j0 + jl], bo = bs[3 * HH + j0 + jl];

    float creg = 0.0f;
    for (int s = 0; s < TT; ++s) {
        const int t  = dir ? (TT - 1 - s) : s;
        const int tp = dir ? t + 1 : t - 1;
        floatx4 acc[2][2];
        acc[0][0] = (floatx4)0.f; acc[0][1] = (floatx4)0.f;
        acc[1][0] = (floatx4)0.f; acc[1][1] = (floatx4)0.f;

        const f16* xrow = xT + (size_t)t * BB * XPAD;
        const f16* hrow = h1 + (size_t)tp * BB * KROW + dir * HH;   // valid iff s>0
#pragma unroll
        for (int i = 0; i < 7; ++i) {
            const int ktg = kt0 + i;
            if (ktg < kt1) {
                const bool isx = (ktg < 2);
                if (isx || s > 0) {
                    half8 b0, b1;
                    if (isx) {
                        const f16* p = xrow + ktg * 32 + quad * 8;
                        b0 = *(const half8*)(p + (size_t)l15 * XPAD);
                        b1 = *(const half8*)(p + (size_t)(16 + l15) * XPAD);
                    } else {
                        const f16* p = hrow + (ktg - 2) * 32 + quad * 8;
                        b0 = *(const half8*)(p + (size_t)l15 * KROW);
                        b1 = *(const half8*)(p + (size_t)(16 + l15) * KROW);
                    }
                    acc[0][0] = __builtin_amdgcn_mfma_f32_16x16x32_f16(afr[0][i], b0, acc[0][0], 0, 0, 0);
                    acc[0][1] = __builtin_amdgcn_mfma_f32_16x16x32_f16(afr[0][i], b1, acc[0][1], 0, 0, 0);
                    acc[1][0] = __builtin_amdgcn_mfma_f32_16x16x32_f16(afr[1][i], b0, acc[1][0], 0, 0, 0);
                    acc[1][1] = __builtin_amdgcn_mfma_f32_16x16x32_f16(afr[1][i], b1, acc[1][1], 0, 0, 0);
                }
            }
        }
        // per-wave partials -> LDS   (D layout: row = quad*4+reg, col = l15)
#pragma unroll
        for (int mt = 0; mt < 2; ++mt)
#pragma unroll
            for (int nt = 0; nt < 2; ++nt)
#pragma unroll
                for (int rg = 0; rg < 4; ++rg)
                    gbuf[w][mt * 16 + quad * 4 + rg][nt * 16 + l15] = acc[mt][nt][rg];
        __syncthreads();
        {   // epilogue: thread (jl, bb)
            float gi_ = bi, gf_ = bf, gc_ = bg, go_ = bo;
#pragma unroll
            for (int ww = 0; ww < 4; ++ww) {
                gi_ += gbuf[ww][jl][bb];
                gf_ += gbuf[ww][8 + jl][bb];
                gc_ += gbuf[ww][16 + jl][bb];
                go_ += gbuf[ww][24 + jl][bb];
            }
            const float cn = sigm(gf_) * creg + sigm(gi_) * tanhf(gc_);
            creg = cn;
            hbuf[bb * 8 + jl] = (f16)(sigm(go_) * tanhf(cn));
        }
        __syncthreads();
        if (tid < BB)
            *(half8*)(h1 + ((size_t)t * BB + tid) * KROW + dir * HH + j0) =
                *(const half8*)(hbuf + tid * 8);
        fbar(flags, BPD, blk, (unsigned)(s + 1));
    }
}

// ===========================================================================
// rnn1: layer 1.  K = 1600 (h1[t], both dirs) + 800 (h2 prev) = 75 k-steps.
// ===========================================================================
__global__ __launch_bounds__(256, 1) void rnn1_kernel(
    const f16* __restrict__ h1, f16* __restrict__ h2,
    const float* __restrict__ Wih_f1, const float* __restrict__ Whh_f1, const float* __restrict__ b_f1,
    const float* __restrict__ Wih_b1, const float* __restrict__ Whh_b1, const float* __restrict__ b_b1,
    unsigned* __restrict__ fl)
{
    __shared__ float gbuf[4][32][33];
    __shared__ f16  hbuf[256];

    const int tid  = threadIdx.x;
    const int dir  = blockIdx.x / BPD;
    const int blk  = blockIdx.x % BPD;
    const int j0   = blk * 8;
    const int w    = tid >> 6;
    const int lane = tid & 63;
    const int l15  = lane & 15;
    const int quad = lane >> 4;
    const int jl   = tid >> 5;
    const int bb   = tid & 31;

    unsigned* flags = fl + dir * 128;

    const float* Wih = dir ? Wih_b1 : Wih_f1;
    const float* Whh = dir ? Whh_b1 : Whh_f1;
    const float* bs  = dir ? b_b1  : b_f1;

    const int kt0 = (w * 75) >> 2;          // 0,18,37,56
    const int kt1 = ((w + 1) * 75) >> 2;    // 18,37,56,75

    half8 afr[2][19];                       // 152 VGPRs of weights
#pragma unroll
    for (int mt = 0; mt < 2; ++mt) {
        const int r = mt * 16 + l15;
        const int grow = (r >> 3) * HH + j0 + (r & 7);
#pragma unroll
        for (int i = 0; i < 19; ++i) {
            const int ktg = kt0 + i;
            half8 v;
#pragma unroll
            for (int jj = 0; jj < 8; ++jj) v[jj] = (f16)0.f;
            if (ktg < kt1) {
                if (ktg < 50) v = cvt8(Wih + (size_t)grow * KROW + ktg * 32 + quad * 8);
                else          v = cvt8(Whh + (size_t)grow * HH + (ktg - 50) * 32 + quad * 8);
            }
            afr[mt][i] = v;
        }
    }
    const float bi = bs[0 * HH + j0 + jl], bf = bs[1 * HH + j0 + jl],
                bg = bs[2 * HH + j0 + jl], bo = bs[3 * HH + j0 + jl];

    float creg = 0.0f;
    for (int s = 0; s < TT; ++s) {
        const int t  = dir ? (TT - 1 - s) : s;
        const int tp = dir ? t + 1 : t - 1;
        floatx4 acc[2][2];
        acc[0][0] = (floatx4)0.f; acc[0][1] = (floatx4)0.f;
        acc[1][0] = (floatx4)0.f; acc[1][1] = (floatx4)0.f;

        const f16* h1row = h1 + (size_t)t * BB * KROW;               // static input
        const f16* h2row = h2 + (size_t)tp * BB * KROW + dir * HH;   // valid iff s>0
#pragma unroll
        for (int i = 0; i < 19; ++i) {
            const int ktg = kt0 + i;
            if (ktg < kt1) {
                const bool isin = (ktg < 50);
                if (isin || s > 0) {
                    half8 b0, b1;
                    if (isin) {
                        const f16* p = h1row + ktg * 32 + quad * 8;
                        b0 = *(const half8*)(p + (size_t)l15 * KROW);
                        b1 = *(const half8*)(p + (size_t)(16 + l15) * KROW);
                    } else {
                        const f16* p = h2row + (ktg - 50) * 32 + quad * 8;
                        b0 = *(const half8*)(p + (size_t)l15 * KROW);
                        b1 = *(const half8*)(p + (size_t)(16 + l15) * KROW);
                    }
                    acc[0][0] = __builtin_amdgcn_mfma_f32_16x16x32_f16(afr[0][i], b0, acc[0][0], 0, 0, 0);
                    acc[0][1] = __builtin_amdgcn_mfma_f32_16x16x32_f16(afr[0][i], b1, acc[0][1], 0, 0, 0);
                    acc[1][0] = __builtin_amdgcn_mfma_f32_16x16x32_f16(afr[1][i], b0, acc[1][0], 0, 0, 0);
                    acc[1][1] = __builtin_amdgcn_mfma_f32_16x16x32_f16(afr[1][i], b1, acc[1][1], 0, 0, 0);
                }
            }
        }
#pragma unroll
        for (int mt = 0; mt < 2; ++mt)
#pragma unroll
            for (int nt = 0; nt < 2; ++nt)
#pragma unroll
                for (int rg = 0; rg < 4; ++rg)
                    gbuf[w][mt * 16 + quad * 4 + rg][nt * 16 + l15] = acc[mt][nt][rg];
        __syncthreads();
        {
            float gi_ = bi, gf_ = bf, gc_ = bg, go_ = bo;
#pragma unroll
            for (int ww = 0; ww < 4; ++ww) {
                gi_ += gbuf[ww][jl][bb];
                gf_ += gbuf[ww][8 + jl][bb];
                gc_ += gbuf[ww][16 + jl][bb];
                go_ += gbuf[ww][24 + jl][bb];
            }
            const float cn = sigm(gf_) * creg + sigm(gi_) * tanhf(gc_);
            creg = cn;
            hbuf[bb * 8 + jl] = (f16)(sigm(go_) * tanhf(cn));
        }
        __syncthreads();
        if (tid < BB)
            *(half8*)(h2 + ((size_t)t * BB + tid) * KROW + dir * HH + j0) =
                *(const half8*)(hbuf + tid * 8);
        fbar(flags, BPD, blk, (unsigned)(s + 1));
    }
}

// ---------------------------------------------------------------------------
// prep: xT f16 [t][b][64] zero-padded, sin/cos tables, zero all barrier flags
__global__ void prep_kernel(const float* __restrict__ x, const float* __restrict__ alphabet,
                            f16* __restrict__ xT, float* __restrict__ sin_t,
                            float* __restrict__ cos_t, unsigned* __restrict__ fl) {
    const int gid = blockIdx.x * blockDim.x + threadIdx.x;
    const int nth = gridDim.x * blockDim.x;
    for (int idx = gid; idx < TT * BB * XPAD; idx += nth) {
        const int tb = idx >> 6;            // t*32+b
        const int i  = idx & 63;
        xT[idx] = (i < DIN) ? (f16)x[(size_t)tb * DIN + i] : (f16)0.f;
    }
    if (gid < 60) { sin_t[gid] = sinf(alphabet[gid]); cos_t[gid] = cosf(alphabet[gid]); }
    if (gid < 512) fl[gid] = 0u;
}

// logits -> softmax -> dihedral angles (h2 f16, [t][b][k])
__global__ __launch_bounds__(640, 1) void head_kernel(
    const f16* __restrict__ h2, const float* __restrict__ Wl, const float* __restrict__ bl,
    const float* __restrict__ sin_t, const float* __restrict__ cos_t,
    float* __restrict__ angles) {
    __shared__ float pl[20][33];
    __shared__ float mx[32];
    const int t = blockIdx.x;
    const int a = threadIdx.x / 32;
    const int b = threadIdx.x & 31;
    if (a < 20) {
        float acc = bl[a];
        const float* wr = Wl + (size_t)a * KROW;
        const f16*   hr = h2 + ((size_t)t * BB + b) * KROW;
        for (int k8 = 0; k8 < KROW / 8; ++k8) {
            const half8 hv = *(const half8*)(hr + k8 * 8);
#pragma unroll
            for (int j = 0; j < 8; ++j) acc = fmaf(wr[k8 * 8 + j], (float)hv[j], acc);
        }
        pl[a][b] = acc;
    }
    __syncthreads();
    if (threadIdx.x < 32) {
        float m = pl[0][threadIdx.x];
        for (int i = 1; i < 20; ++i) m = fmaxf(m, pl[i][threadIdx.x]);
        mx[threadIdx.x] = m;
    }
    __syncthreads();
    if (a < 20) pl[a][b] = expf(pl[a][b] - mx[b]);
    __syncthreads();
    if (threadIdx.x < 96) {
        const int c = threadIdx.x / 32, b2 = threadIdx.x & 31;
        float y = 0.f, xx = 0.f;
        for (int i = 0; i < 20; ++i) {
            const float e = pl[i][b2];
            y  = fmaf(e, sin_t[i * 3 + c], y);
            xx = fmaf(e, cos_t[i * 3 + c], xx);
        }
        angles[((size_t)t * BB + b2) * 3 + c] = atan2f(y, xx);
    }
}

// sequential NeRF coordinate extension, one lane per batch element
__global__ void coords_kernel(const float* __restrict__ angles, float* __restrict__ out) {
    const int b = threadIdx.x;
    if (b >= BB) return;
    const float rs[3]  = {1.458f, 1.525f, 1.33f};
    const float ths[3] = {2.124f, 1.941f, 2.028f};
    float ct[3], st[3];
#pragma unroll
    for (int k = 0; k < 3; ++k) { ct[k] = cosf(ths[k]); st[k] = sinf(ths[k]); }
    float pax = 0.f,     pay = 0.f, paz = 0.f;
    float pbx = 1.458f,  pby = 0.f, pbz = 0.f;
    float pcx = 2.f,     pcy = 1.f, pcz = 0.f;
    for (int n = 0; n < 3 * TT; ++n) {
        const int t = n / 3;
        const int k = n - 3 * t;
        const float phi = angles[((size_t)t * BB + b) * 3 + k];
        float ux = pcx - pbx, uy = pcy - pby, uz = pcz - pbz;
        const float il = rsqrtf(ux * ux + uy * uy + uz * uz);
        const float bcx = ux * il, bcy = uy * il, bcz = uz * il;
        const float wx = pbx - pax, wy = pby - pay, wz = pbz - paz;
        float cx = wy * bcz - wz * bcy, cy = wz * bcx - wx * bcz, cz = wx * bcy - wy * bcx;
        const float iln = rsqrtf(cx * cx + cy * cy + cz * cz);
        const float nx = cx * iln, ny = cy * iln, nz = cz * iln;
        const float mxv = ny * bcz - nz * bcy, myv = nz * bcx - nx * bcz, mzv = nx * bcy - ny * bcx;
        float sp, cp;
        __sincosf(phi, &sp, &cp);
        const float rr = rs[k], cth = ct[k], sth = st[k];
        const float dx = pcx - rr * cth * bcx + rr * sth * (cp * mxv + sp * nx);
        const float dy = pcy - rr * cth * bcy + rr * sth * (cp * myv + sp * ny);
        const float dz = pcz - rr * cth * bcz + rr * sth * (cp * mzv + sp * nz);
        float* o = out + ((size_t)n * BB + b) * 3;
        o[0] = dx; o[1] = dy; o[2] = dz;
        pax = pbx; pay = pby; paz = pbz;
        pbx = pcx; pby = pcy; pbz = pcz;
        pcx = dx;  pcy = dy;  pcz = dz;
    }
}

// ---------------------------------------------------------------------------
extern "C" void kernel_launch(void* const* d_in, const int* in_sizes, int n_in,
                              void* d_out, int out_size, void* d_ws, size_t ws_size,
                              hipStream_t stream) {
    (void)in_sizes; (void)n_in; (void)out_size; (void)ws_size;
    const float* x      = (const float*)d_in[0];
    const float* Wih_f0 = (const float*)d_in[1];
    const float* Whh_f0 = (const float*)d_in[2];
    const float* b_f0   = (const float*)d_in[3];
    const float* Wih_b0 = (const float*)d_in[4];
    const float* Whh_b0 = (const float*)d_in[5];
    const float* b_b0   = (const float*)d_in[6];
    const float* Wih_f1 = (const float*)d_in[7];
    const float* Whh_f1 = (const float*)d_in[8];
    const float* b_f1   = (const float*)d_in[9];
    const float* Wih_b1 = (const float*)d_in[10];
    const float* Whh_b1 = (const float*)d_in[11];
    const float* b_b1   = (const float*)d_in[12];
    const float* Wl     = (const float*)d_in[13];
    const float* bl     = (const float*)d_in[14];
    const float* alphabet = (const float*)d_in[15];

    float* ws = (float*)d_ws;
    unsigned* fl0 = (unsigned*)d_ws;          // rnn0 flags [2][128]
    unsigned* fl1 = (unsigned*)d_ws + 256;    // rnn1 flags [2][128]
    f16*   xT     = (f16*)(ws + OFF_XT);
    f16*   h1     = (f16*)(ws + OFF_H1);
    f16*   h2     = (f16*)(ws + OFF_H2);
    float* angles = ws + OFF_ANG;
    float* sin_t  = ws + OFF_SIN;
    float* cos_t  = ws + OFF_COS;

    prep_kernel<<<1024, 256, 0, stream>>>(x, alphabet, xT, sin_t, cos_t, (unsigned*)d_ws);
    rnn0_kernel<<<NBLK, 256, 0, stream>>>(xT, h1,
        Wih_f0, Whh_f0, b_f0, Wih_b0, Whh_b0, b_b0, fl0);
    rnn1_kernel<<<NBLK, 256, 0, stream>>>(h1, h2,
        Wih_f1, Whh_f1, b_f1, Wih_b1, Whh_b1, b_b1, fl1);
    head_kernel<<<TT, 640, 0, stream>>>(h2, Wl, bl, sin_t, cos_t, angles);
    coords_kernel<<<1, 64, 0, stream>>>(angles, (float*)d_out);
}

// Round 5
// 8988.435 us; speedup vs baseline: 5.4292x; 1.9022x over previous
//
#include <hip/hip_runtime.h>
#include <math.h>

// ---------------------------------------------------------------------------
// RGN: 2-layer biLSTM (T=512,B=32,H=800) -> linear/softmax/dihedral -> NeRF chain
// Round 5: coherence by LLC-bypass instead of cache maintenance.
//   R4 post-mortem: flag barrier didn't help (19us/step unchanged) -> the cost
//   is the per-step agent acquire/release (buffer_inv/buffer_wbl2 = full L2
//   maintenance per block per step) + forced LLC refill of everything.
//   Now: NO fences in the step loop.
//     - recurrent state (h1 in rnn0, h2 in rnn1): agent-scope RELAXED atomic
//       u64 loads/stores -> write-through/read-through at the coherent LLC.
//     - static data (xT, h1-in-rnn1, weights): plain cacheable loads; stays
//       L2-resident across steps since nothing invalidates L2 anymore.
//     - barrier: own-cacheline flag per block (relaxed store after
//       __syncthreads, which drains vmcnt -> stores visible), parallel poll.
// ---------------------------------------------------------------------------

#define TT 512
#define BB 32
#define HH 800
#define DIN 41
#define XPAD 64                // x padded to 64 cols (zeros) -> 2 clean k-steps
#define KROW 1600              // h row length in k (both directions packed)
#define NBLK 200
#define BPD 100                // blocks per direction
#define FPAD 16                // one 64B cacheline per flag

typedef _Float16 f16;
typedef _Float16 half8 __attribute__((ext_vector_type(8)));
typedef float floatx4 __attribute__((ext_vector_type(4)));

// ---------------- workspace layout (float-slot offsets), total ~107 MB -----
// u32[0..6400): flags: [kernel(2)][dir(2)][BPD(100)][FPAD(16)]
#define OFF_XT   8192                       // f16 [512][32][64]    (524288 slots)
#define OFF_H1   (OFF_XT + 524288)          // f16 [512][32][1600]  (13107200 slots)
#define OFF_H2   (OFF_H1 + 13107200)        // f16 [512][32][1600]  (13107200 slots)
#define OFF_ANG  (OFF_H2 + 13107200)        // f32 [512][32][3]     (49152)
#define OFF_SIN  (OFF_ANG + 49152)
#define OFF_COS  (OFF_SIN + 64)

__device__ __forceinline__ float sigm(float x) { return 1.0f / (1.0f + expf(-x)); }

union U64H8 { unsigned long long u[2]; half8 h; };

// 16B load/store through the coherent point (LLC), no cache maintenance needed.
__device__ __forceinline__ half8 ald16(const f16* p) {
    U64H8 x;
    x.u[0] = __hip_atomic_load((const unsigned long long*)p,     __ATOMIC_RELAXED, __HIP_MEMORY_SCOPE_AGENT);
    x.u[1] = __hip_atomic_load((const unsigned long long*)p + 1, __ATOMIC_RELAXED, __HIP_MEMORY_SCOPE_AGENT);
    return x.h;
}
__device__ __forceinline__ void ast16(f16* p, half8 v) {
    U64H8 x; x.h = v;
    __hip_atomic_store((unsigned long long*)p,     x.u[0], __ATOMIC_RELAXED, __HIP_MEMORY_SCOPE_AGENT);
    __hip_atomic_store((unsigned long long*)p + 1, x.u[1], __ATOMIC_RELAXED, __HIP_MEMORY_SCOPE_AGENT);
}

// Flag-array grid barrier, own direction only. Monotonic -> lap-safe.
// Preceding __syncthreads drains vmcnt per thread before s_barrier, so all
// agent-scope write-through stores are LLC-visible before the flag store.
__device__ __forceinline__ void fbar(unsigned* flags, int myidx, unsigned target) {
    __syncthreads();
    if (threadIdx.x < 64) {
        if (threadIdx.x == 0)
            __hip_atomic_store(&flags[myidx * FPAD], target, __ATOMIC_RELAXED, __HIP_MEMORY_SCOPE_AGENT);
        for (;;) {
            unsigned v = target;
            for (int i = (int)threadIdx.x; i < BPD; i += 64) {
                const unsigned f = __hip_atomic_load(&flags[i * FPAD], __ATOMIC_RELAXED, __HIP_MEMORY_SCOPE_AGENT);
                v = (f < v) ? f : v;
            }
#pragma unroll
            for (int off = 1; off < 64; off <<= 1) {
                const unsigned o = (unsigned)__shfl_xor((int)v, off, 64);
                v = (o < v) ? o : v;
            }
            if (v >= target) break;
            __builtin_amdgcn_s_sleep(1);
        }
    }
    __syncthreads();
}

__device__ __forceinline__ half8 cvt8(const float* p) {
    half8 r;
#pragma unroll
    for (int i = 0; i < 8; ++i) r[i] = (f16)p[i];
    return r;
}

// ===========================================================================
// rnn0: layer 0.  K = 64 (xT, plain/cached) + 800 (h1 prev, bypass) per dir.
// ===========================================================================
__global__ __launch_bounds__(256, 1) void rnn0_kernel(
    const f16* __restrict__ xT, f16* __restrict__ h1,
    const float* __restrict__ Wih_f0, const float* __restrict__ Whh_f0, const float* __restrict__ b_f0,
    const float* __restrict__ Wih_b0, const float* __restrict__ Whh_b0, const float* __restrict__ b_b0,
    unsigned* __restrict__ fl)
{
    __shared__ float gbuf[4][32][33];
    __shared__ f16  hbuf[256];

    const int tid  = threadIdx.x;
    const int dir  = blockIdx.x / BPD;
    const int blk  = blockIdx.x % BPD;
    const int j0   = blk * 8;
    const int w    = tid >> 6;          // wave id = k-slice
    const int lane = tid & 63;
    const int l15  = lane & 15;
    const int quad = lane >> 4;
    const int jl   = tid >> 5;          // epilogue: hidden unit 0..7
    const int bb   = tid & 31;          // epilogue: batch

    unsigned* flags = fl + dir * BPD * FPAD;

    const float* Wih = dir ? Wih_b0 : Wih_f0;
    const float* Whh = dir ? Whh_b0 : Whh_f0;
    const float* bs  = dir ? b_b0  : b_f0;

    const int kt0 = (w * 27) >> 2;          // 0,6,13,20
    const int kt1 = ((w + 1) * 27) >> 2;    // 6,13,20,27

    // A-fragments in registers: afr[mt][i] = W[row mt*16+l15][k = (kt0+i)*32 + quad*8 ..+7]
    half8 afr[2][7];
#pragma unroll
    for (int mt = 0; mt < 2; ++mt) {
        const int r = mt * 16 + l15;
        const int grow = (r >> 3) * HH + j0 + (r & 7);
#pragma unroll
        for (int i = 0; i < 7; ++i) {
            const int ktg = kt0 + i;
            half8 v;
#pragma unroll
            for (int jj = 0; jj < 8; ++jj) v[jj] = (f16)0.f;
            if (ktg < kt1) {
                if (ktg < 2) {          // Wih cols (41 wide, zero-padded to 64)
#pragma unroll
                    for (int jj = 0; jj < 8; ++jj) {
                        const int k = ktg * 32 + quad * 8 + jj;
                        if (k < DIN) v[jj] = (f16)Wih[(size_t)grow * DIN + k];
                    }
                } else {                // Whh cols
                    v = cvt8(Whh + (size_t)grow * HH + (ktg - 2) * 32 + quad * 8);
                }
            }
            afr[mt][i] = v;
        }
    }
    const float bi = bs[0 * HH + j0 + jl], bf = bs[1 * HH + j0 + jl],
                bg = bs[2 * HH + j0 + jl], bo = bs[3 * HH + j0 + jl];

    float creg = 0.0f;
    for (int s = 0; s < TT; ++s) {
        const int t  = dir ? (TT - 1 - s) : s;
        const int tp = dir ? t + 1 : t - 1;
        floatx4 acc[2][2];
        acc[0][0] = (floatx4)0.f; acc[0][1] = (floatx4)0.f;
        acc[1][0] = (floatx4)0.f; acc[1][1] = (floatx4)0.f;

        const f16* xrow = xT + (size_t)t * BB * XPAD;                // static: cached
        const f16* hrow = h1 + (size_t)tp * BB * KROW + dir * HH;    // dynamic: bypass
#pragma unroll
        for (int i = 0; i < 7; ++i) {
            const int ktg = kt0 + i;
            if (ktg < kt1) {
                const bool isx = (ktg < 2);
                if (isx || s > 0) {
                    half8 b0, b1;
                    if (isx) {
                        const f16* p = xrow + ktg * 32 + quad * 8;
                        b0 = *(const half8*)(p + (size_t)l15 * XPAD);
                        b1 = *(const half8*)(p + (size_t)(16 + l15) * XPAD);
                    } else {
                        const f16* p = hrow + (ktg - 2) * 32 + quad * 8;
                        b0 = ald16(p + (size_t)l15 * KROW);
                        b1 = ald16(p + (size_t)(16 + l15) * KROW);
                    }
                    acc[0][0] = __builtin_amdgcn_mfma_f32_16x16x32_f16(afr[0][i], b0, acc[0][0], 0, 0, 0);
                    acc[0][1] = __builtin_amdgcn_mfma_f32_16x16x32_f16(afr[0][i], b1, acc[0][1], 0, 0, 0);
                    acc[1][0] = __builtin_amdgcn_mfma_f32_16x16x32_f16(afr[1][i], b0, acc[1][0], 0, 0, 0);
                    acc[1][1] = __builtin_amdgcn_mfma_f32_16x16x32_f16(afr[1][i], b1, acc[1][1], 0, 0, 0);
                }
            }
        }
        // per-wave partials -> LDS   (D layout: row = quad*4+reg, col = l15)
#pragma unroll
        for (int mt = 0; mt < 2; ++mt)
#pragma unroll
            for (int nt = 0; nt < 2; ++nt)
#pragma unroll
                for (int rg = 0; rg < 4; ++rg)
                    gbuf[w][mt * 16 + quad * 4 + rg][nt * 16 + l15] = acc[mt][nt][rg];
        __syncthreads();
        {   // epilogue: thread (jl, bb)
            float gi_ = bi, gf_ = bf, gc_ = bg, go_ = bo;
#pragma unroll
            for (int ww = 0; ww < 4; ++ww) {
                gi_ += gbuf[ww][jl][bb];
                gf_ += gbuf[ww][8 + jl][bb];
                gc_ += gbuf[ww][16 + jl][bb];
                go_ += gbuf[ww][24 + jl][bb];
            }
            const float cn = sigm(gf_) * creg + sigm(gi_) * tanhf(gc_);
            creg = cn;
            hbuf[bb * 8 + jl] = (f16)(sigm(go_) * tanhf(cn));
        }
        __syncthreads();
        if (tid < BB)
            ast16(h1 + ((size_t)t * BB + tid) * KROW + dir * HH + j0,
                  *(const half8*)(hbuf + tid * 8));
        fbar(flags, blk, (unsigned)(s + 1));
    }
}

// ===========================================================================
// rnn1: layer 1.  K = 1600 (h1[t], plain/cached) + 800 (h2 prev, bypass).
// ===========================================================================
__global__ __launch_bounds__(256, 1) void rnn1_kernel(
    const f16* __restrict__ h1, f16* __restrict__ h2,
    const float* __restrict__ Wih_f1, const float* __restrict__ Whh_f1, const float* __restrict__ b_f1,
    const float* __restrict__ Wih_b1, const float* __restrict__ Whh_b1, const float* __restrict__ b_b1,
    unsigned* __restrict__ fl)
{
    __shared__ float gbuf[4][32][33];
    __shared__ f16  hbuf[256];

    const int tid  = threadIdx.x;
    const int dir  = blockIdx.x / BPD;
    const int blk  = blockIdx.x % BPD;
    const int j0   = blk * 8;
    const int w    = tid >> 6;
    const int lane = tid & 63;
    const int l15  = lane & 15;
    const int quad = lane >> 4;
    const int jl   = tid >> 5;
    const int bb   = tid & 31;

    unsigned* flags = fl + dir * BPD * FPAD;

    const float* Wih = dir ? Wih_b1 : Wih_f1;
    const float* Whh = dir ? Whh_b1 : Whh_f1;
    const float* bs  = dir ? b_b1  : b_f1;

    const int kt0 = (w * 75) >> 2;          // 0,18,37,56
    const int kt1 = ((w + 1) * 75) >> 2;    // 18,37,56,75

    half8 afr[2][19];                       // weight fragments (VGPR/AGPR resident)
#pragma unroll
    for (int mt = 0; mt < 2; ++mt) {
        const int r = mt * 16 + l15;
        const int grow = (r >> 3) * HH + j0 + (r & 7);
#pragma unroll
        for (int i = 0; i < 19; ++i) {
            const int ktg = kt0 + i;
            half8 v;
#pragma unroll
            for (int jj = 0; jj < 8; ++jj) v[jj] = (f16)0.f;
            if (ktg < kt1) {
                if (ktg < 50) v = cvt8(Wih + (size_t)grow * KROW + ktg * 32 + quad * 8);
                else          v = cvt8(Whh + (size_t)grow * HH + (ktg - 50) * 32 + quad * 8);
            }
            afr[mt][i] = v;
        }
    }
    const float bi = bs[0 * HH + j0 + jl], bf = bs[1 * HH + j0 + jl],
                bg = bs[2 * HH + j0 + jl], bo = bs[3 * HH + j0 + jl];

    float creg = 0.0f;
    for (int s = 0; s < TT; ++s) {
        const int t  = dir ? (TT - 1 - s) : s;
        const int tp = dir ? t + 1 : t - 1;
        floatx4 acc[2][2];
        acc[0][0] = (floatx4)0.f; acc[0][1] = (floatx4)0.f;
        acc[1][0] = (floatx4)0.f; acc[1][1] = (floatx4)0.f;

        const f16* h1row = h1 + (size_t)t * BB * KROW;               // static: cached
        const f16* h2row = h2 + (size_t)tp * BB * KROW + dir * HH;   // dynamic: bypass
#pragma unroll
        for (int i = 0; i < 19; ++i) {
            const int ktg = kt0 + i;
            if (ktg < kt1) {
                const bool isin = (ktg < 50);
                if (isin || s > 0) {
                    half8 b0, b1;
                    if (isin) {
                        const f16* p = h1row + ktg * 32 + quad * 8;
                        b0 = *(const half8*)(p + (size_t)l15 * KROW);
                        b1 = *(const half8*)(p + (size_t)(16 + l15) * KROW);
                    } else {
                        const f16* p = h2row + (ktg - 50) * 32 + quad * 8;
                        b0 = ald16(p + (size_t)l15 * KROW);
                        b1 = ald16(p + (size_t)(16 + l15) * KROW);
                    }
                    acc[0][0] = __builtin_amdgcn_mfma_f32_16x16x32_f16(afr[0][i], b0, acc[0][0], 0, 0, 0);
                    acc[0][1] = __builtin_amdgcn_mfma_f32_16x16x32_f16(afr[0][i], b1, acc[0][1], 0, 0, 0);
                    acc[1][0] = __builtin_amdgcn_mfma_f32_16x16x32_f16(afr[1][i], b0, acc[1][0], 0, 0, 0);
                    acc[1][1] = __builtin_amdgcn_mfma_f32_16x16x32_f16(afr[1][i], b1, acc[1][1], 0, 0, 0);
                }
            }
        }
#pragma unroll
        for (int mt = 0; mt < 2; ++mt)
#pragma unroll
            for (int nt = 0; nt < 2; ++nt)
#pragma unroll
                for (int rg = 0; rg < 4; ++rg)
                    gbuf[w][mt * 16 + quad * 4 + rg][nt * 16 + l15] = acc[mt][nt][rg];
        __syncthreads();
        {
            float gi_ = bi, gf_ = bf, gc_ = bg, go_ = bo;
#pragma unroll
            for (int ww = 0; ww < 4; ++ww) {
                gi_ += gbuf[ww][jl][bb];
                gf_ += gbuf[ww][8 + jl][bb];
                gc_ += gbuf[ww][16 + jl][bb];
                go_ += gbuf[ww][24 + jl][bb];
            }
            const float cn = sigm(gf_) * creg + sigm(gi_) * tanhf(gc_);
            creg = cn;
            hbuf[bb * 8 + jl] = (f16)(sigm(go_) * tanhf(cn));
        }
        __syncthreads();
        if (tid < BB)
            ast16(h2 + ((size_t)t * BB + tid) * KROW + dir * HH + j0,
                  *(const half8*)(hbuf + tid * 8));
        fbar(flags, blk, (unsigned)(s + 1));
    }
}

// ---------------------------------------------------------------------------
// prep: xT f16 [t][b][64] zero-padded, sin/cos tables, zero all barrier flags
__global__ void prep_kernel(const float* __restrict__ x, const float* __restrict__ alphabet,
                            f16* __restrict__ xT, float* __restrict__ sin_t,
                            float* __restrict__ cos_t, unsigned* __restrict__ fl) {
    const int gid = blockIdx.x * blockDim.x + threadIdx.x;
    const int nth = gridDim.x * blockDim.x;
    for (int idx = gid; idx < TT * BB * XPAD; idx += nth) {
        const int tb = idx >> 6;            // t*32+b
        const int i  = idx & 63;
        xT[idx] = (i < DIN) ? (f16)x[(size_t)tb * DIN + i] : (f16)0.f;
    }
    if (gid < 60) { sin_t[gid] = sinf(alphabet[gid]); cos_t[gid] = cosf(alphabet[gid]); }
    if (gid < 2 * 2 * BPD * FPAD) fl[gid] = 0u;
}

// logits -> softmax -> dihedral angles (h2 f16, [t][b][k])
__global__ __launch_bounds__(640, 1) void head_kernel(
    const f16* __restrict__ h2, const float* __restrict__ Wl, const float* __restrict__ bl,
    const float* __restrict__ sin_t, const float* __restrict__ cos_t,
    float* __restrict__ angles) {
    __shared__ float pl[20][33];
    __shared__ float mx[32];
    const int t = blockIdx.x;
    const int a = threadIdx.x / 32;
    const int b = threadIdx.x & 31;
    if (a < 20) {
        float acc = bl[a];
        const float* wr = Wl + (size_t)a * KROW;
        const f16*   hr = h2 + ((size_t)t * BB + b) * KROW;
        for (int k8 = 0; k8 < KROW / 8; ++k8) {
            const half8 hv = *(const half8*)(hr + k8 * 8);
#pragma unroll
            for (int j = 0; j < 8; ++j) acc = fmaf(wr[k8 * 8 + j], (float)hv[j], acc);
        }
        pl[a][b] = acc;
    }
    __syncthreads();
    if (threadIdx.x < 32) {
        float m = pl[0][threadIdx.x];
        for (int i = 1; i < 20; ++i) m = fmaxf(m, pl[i][threadIdx.x]);
        mx[threadIdx.x] = m;
    }
    __syncthreads();
    if (a < 20) pl[a][b] = expf(pl[a][b] - mx[b]);
    __syncthreads();
    if (threadIdx.x < 96) {
        const int c = threadIdx.x / 32, b2 = threadIdx.x & 31;
        float y = 0.f, xx = 0.f;
        for (int i = 0; i < 20; ++i) {
            const float e = pl[i][b2];
            y  = fmaf(e, sin_t[i * 3 + c], y);
            xx = fmaf(e, cos_t[i * 3 + c], xx);
        }
        angles[((size_t)t * BB + b2) * 3 + c] = atan2f(y, xx);
    }
}

// sequential NeRF coordinate extension, one lane per batch element
__global__ void coords_kernel(const float* __restrict__ angles, float* __restrict__ out) {
    const int b = threadIdx.x;
    if (b >= BB) return;
    const float rs[3]  = {1.458f, 1.525f, 1.33f};
    const float ths[3] = {2.124f, 1.941f, 2.028f};
    float ct[3], st[3];
#pragma unroll
    for (int k = 0; k < 3; ++k) { ct[k] = cosf(ths[k]); st[k] = sinf(ths[k]); }
    float pax = 0.f,     pay = 0.f, paz = 0.f;
    float pbx = 1.458f,  pby = 0.f, pbz = 0.f;
    float pcx = 2.f,     pcy = 1.f, pcz = 0.f;
    for (int n = 0; n < 3 * TT; ++n) {
        const int t = n / 3;
        const int k = n - 3 * t;
        const float phi = angles[((size_t)t * BB + b) * 3 + k];
        float ux = pcx - pbx, uy = pcy - pby, uz = pcz - pbz;
        const float il = rsqrtf(ux * ux + uy * uy + uz * uz);
        const float bcx = ux * il, bcy = uy * il, bcz = uz * il;
        const float wx = pbx - pax, wy = pby - pay, wz = pbz - paz;
        float cx = wy * bcz - wz * bcy, cy = wz * bcx - wx * bcz, cz = wx * bcy - wy * bcx;
        const float iln = rsqrtf(cx * cx + cy * cy + cz * cz);
        const float nx = cx * iln, ny = cy * iln, nz = cz * iln;
        const float mxv = ny * bcz - nz * bcy, myv = nz * bcx - nx * bcz, mzv = nx * bcy - ny * bcx;
        float sp, cp;
        __sincosf(phi, &sp, &cp);
        const float rr = rs[k], cth = ct[k], sth = st[k];
        const float dx = pcx - rr * cth * bcx + rr * sth * (cp * mxv + sp * nx);
        const float dy = pcy - rr * cth * bcy + rr * sth * (cp * myv + sp * ny);
        const float dz = pcz - rr * cth * bcz + rr * sth * (cp * mzv + sp * nz);
        float* o = out + ((size_t)n * BB + b) * 3;
        o[0] = dx; o[1] = dy; o[2] = dz;
        pax = pbx; pay = pby; paz = pbz;
        pbx = pcx; pby = pcy; pbz = pcz;
        pcx = dx;  pcy = dy;  pcz = dz;
    }
}

// ---------------------------------------------------------------------------
extern "C" void kernel_launch(void* const* d_in, const int* in_sizes, int n_in,
                              void* d_out, int out_size, void* d_ws, size_t ws_size,
                              hipStream_t stream) {
    (void)in_sizes; (void)n_in; (void)out_size; (void)ws_size;
    const float* x      = (const float*)d_in[0];
    const float* Wih_f0 = (const float*)d_in[1];
    const float* Whh_f0 = (const float*)d_in[2];
    const float* b_f0   = (const float*)d_in[3];
    const float* Wih_b0 = (const float*)d_in[4];
    const float* Whh_b0 = (const float*)d_in[5];
    const float* b_b0   = (const float*)d_in[6];
    const float* Wih_f1 = (const float*)d_in[7];
    const float* Whh_f1 = (const float*)d_in[8];
    const float* b_f1   = (const float*)d_in[9];
    const float* Wih_b1 = (const float*)d_in[10];
    const float* Whh_b1 = (const float*)d_in[11];
    const float* b_b1   = (const float*)d_in[12];
    const float* Wl     = (const float*)d_in[13];
    const float* bl     = (const float*)d_in[14];
    const float* alphabet = (const float*)d_in[15];

    float* ws = (float*)d_ws;
    unsigned* fl0 = (unsigned*)d_ws;                      // rnn0 flags [2][100][16]
    unsigned* fl1 = (unsigned*)d_ws + 2 * BPD * FPAD;     // rnn1 flags [2][100][16]
    f16*   xT     = (f16*)(ws + OFF_XT);
    f16*   h1     = (f16*)(ws + OFF_H1);
    f16*   h2     = (f16*)(ws + OFF_H2);
    float* angles = ws + OFF_ANG;
    float* sin_t  = ws + OFF_SIN;
    float* cos_t  = ws + OFF_COS;

    prep_kernel<<<1024, 256, 0, stream>>>(x, alphabet, xT, sin_t, cos_t, (unsigned*)d_ws);
    rnn0_kernel<<<NBLK, 256, 0, stream>>>(xT, h1,
        Wih_f0, Whh_f0, b_f0, Wih_b0, Whh_b0, b_b0, fl0);
    rnn1_kernel<<<NBLK, 256, 0, stream>>>(h1, h2,
        Wih_f1, Whh_f1, b_f1, Wih_b1, Whh_b1, b_b1, fl1);
    head_kernel<<<TT, 640, 0, stream>>>(h2, Wl, bl, sin_t, cos_t, angles);
    coords_kernel<<<1, 64, 0, stream>>>(angles, (float*)d_out);
}